// Round 1
// baseline (253.041 us; speedup 1.0000x reference)
//
#include <hip/hip_runtime.h>
#include <hip/hip_bf16.h>

// ThresholdEncode: x (N floats in [0,1)) -> (N, 64) float32 spike matrix.
// Row j (j < N-1): col 2i   = (x[j] <= th[i]) & (x[j+1] >  th[i])  (up)
//                  col 2i+1 = (x[j] >  th[i]) & (x[j+1] <= th[i])  (down)
// th[i] = float32( (i+1) * (1/33) computed in double )  -- matches np.linspace
// Row N-1: all zeros.
//
// One thread per output float4 (4 consecutive cols). Wave writes 1 KB
// contiguous -> fully coalesced streaming stores. Memory(write)-bound.

__global__ __launch_bounds__(256) void ThresholdEncode_kernel(
    const float* __restrict__ x, float4* __restrict__ out, int n) {
    const int total = n * 16;              // 16 float4 per row of 64 floats
    const int stride = gridDim.x * blockDim.x;
    for (int idx = blockIdx.x * blockDim.x + threadIdx.x; idx < total; idx += stride) {
        const int j = idx >> 4;            // row
        const int c = idx & 15;            // which float4 within the row
        float4 v = make_float4(0.f, 0.f, 0.f, 0.f);
        if (j < n - 1) {
            const float xp = x[j];
            const float xn = x[j + 1];
            const int i0 = 2 * c;          // threshold indices for this quad
            const int i1 = 2 * c + 1;
            // Exact np.linspace(0,1,34,dtype=f32)[1:-1] semantics:
            // compute in double, round once to float.
            const float t0 = (float)((double)(i0 + 1) * (1.0 / 33.0));
            const float t1 = (float)((double)(i1 + 1) * (1.0 / 33.0));
            v.x = (xp <= t0 && xn >  t0) ? 1.0f : 0.0f;  // up   i0
            v.y = (xp >  t0 && xn <= t0) ? 1.0f : 0.0f;  // down i0
            v.z = (xp <= t1 && xn >  t1) ? 1.0f : 0.0f;  // up   i1
            v.w = (xp >  t1 && xn <= t1) ? 1.0f : 0.0f;  // down i1
        }
        out[idx] = v;
    }
}

extern "C" void kernel_launch(void* const* d_in, const int* in_sizes, int n_in,
                              void* d_out, int out_size, void* d_ws, size_t ws_size,
                              hipStream_t stream) {
    const float* x = (const float*)d_in[0];
    float4* out = (float4*)d_out;
    const int n = in_sizes[0];             // 1,000,000
    const int block = 256;
    const int grid = 4096;                 // grid-stride; 16 blocks/CU
    ThresholdEncode_kernel<<<grid, block, 0, stream>>>(x, out, n);
}